// Round 7
// baseline (528.831 us; speedup 1.0000x reference)
//
#include <hip/hip_runtime.h>
#include <hip/hip_bf16.h>

// ============================================================================
// Head: K=x@Wk^T, Q=x@Wq^T, V=x@Wv^T, causal softmax(QK^T/8)@V
// B=4, T=4096, D=1024, H=64. fp32 I/O, bf16 MFMA compute.
//
// R7 (revert R6's global-V experiment; scale R5's LDS-staged structure):
//  * Back to g2lds V staging + LDS P handoff (R5 @192us), but:
//  * 4 co-resident blocks/CU: 1024 blocks x 256 thr (128q x 128e each),
//    LDS 36KB/block -> 4x144KB, launch_bounds(256,4). Barrier stalls of one
//    block are filled by the other three.
//  * Square wave tiles: wave (wr,wc) does S = 64q x 16s and PV = 64q x 64e.
//    Producer rows == consumer rows (same wr, same activity limit) -> no
//    stale-P hazard; V LDS reads not qs-duplicated beyond 2x.
//  * Per-CU balance: co-resident qt = {h,31-h,15-h,16+h} (sum 62 for all h).
//  * Q frags re-read from L1 each iter (frees 32 persistent VGPRs).
// ============================================================================

typedef __attribute__((ext_vector_type(8))) short bf16x8;   // 8 bf16, 4 VGPRs
typedef __attribute__((ext_vector_type(4))) float f32x4;

typedef unsigned short u16;
typedef unsigned int u32;

__device__ inline u16 f2bf(float f) {
    u32 u = __builtin_bit_cast(u32, f);
    u = (u + 0x7fff + ((u >> 16) & 1)) >> 16;   // RNE
    return (u16)u;
}

__device__ inline void g2lds16(const void* g, void* l) {
    __builtin_amdgcn_global_load_lds(
        (const __attribute__((address_space(1))) unsigned int*)g,
        (__attribute__((address_space(3))) unsigned int*)l, 16, 0, 0);
}

// Fragment-tile addressing (16 rows x 32 k, 512 u16 = 1KB per tile):
//   element (r, k): u16 idx = ((r&15) + ((k>>3)&3)*16)*8 + (k&7)
// A-frag (m=lane&15, k=quad*8+j) and B-frag (n=lane&15, k=quad*8+j) reads are
// both "base + lane*16B" -> coalesced global / conflict-free LDS.

// ----------------------------------------------------------------------------
__global__ void cvt_x(const float* __restrict__ src, u16* __restrict__ dst,
                      int n) {
    const int i = (blockIdx.x * blockDim.x + threadIdx.x) * 4;
    if (i + 3 < n) {
        const float4 v = *(const float4*)(src + i);
        dst[i + 0] = f2bf(v.x);
        dst[i + 1] = f2bf(v.y);
        dst[i + 2] = f2bf(v.z);
        dst[i + 3] = f2bf(v.w);
    }
}

// Fused weight convert: Wk (1x), Wq (x 0.125*log2e), Wv (1x).
__global__ void cvt_w(const float* __restrict__ Wk, const float* __restrict__ Wq,
                      const float* __restrict__ Wv,
                      u16* __restrict__ Wkb, u16* __restrict__ Wqb,
                      u16* __restrict__ Wvb, float qscale) {
    const int i = (blockIdx.x * blockDim.x + threadIdx.x) * 4;
    const float* src; u16* dst; int j; float s = 1.0f;
    if (i < 65536)        { src = Wk; dst = Wkb; j = i; }
    else if (i < 131072)  { src = Wq; dst = Wqb; j = i - 65536; s = qscale; }
    else                  { src = Wv; dst = Wvb; j = i - 131072; }
    const float4 v = *(const float4*)(src + j);
    dst[j + 0] = f2bf(v.x * s);
    dst[j + 1] = f2bf(v.y * s);
    dst[j + 2] = f2bf(v.z * s);
    dst[j + 3] = f2bf(v.w * s);
}

// ----------------------------------------------------------------------------
// GEMM body: C = A[M][K] @ Bsel[N][K]^T, bf16, fp32 accum, 128x128, BK=64.
// lda = ldb = K = 1024. Outputs frag-tiled (MODE 1: Qf/Kf, MODE 2: Vf).
// ----------------------------------------------------------------------------
template <int MODE>
__device__ __forceinline__ void gemm_body(
    int m0, int n0,
    const u16* __restrict__ A,
    const u16* __restrict__ B0, const u16* __restrict__ B1, int nsplit,
    u16* __restrict__ D0, u16* __restrict__ D1,
    u16* Alds, u16* Blds)
{
    const int tid  = threadIdx.x;
    const int lane = tid & 63, w = tid >> 6;
    const int quad = lane >> 4, l15 = lane & 15;
    const int wr = w >> 1, wc = w & 1;
    const int mrow0 = wr * 64, ncol0 = wc * 64;

    f32x4 acc[4][4] = {};

    const int srow = (lane >> 3);
    const int scol = (lane & 7) * 8;

    for (int k0 = 0; k0 < 1024; k0 += 64) {
        __syncthreads();
#pragma unroll
        for (int c = 0; c < 4; ++c) {
            const int chunk = c * 4 + w;
            const int row = chunk * 8 + srow;
            const u16* ga = A + (size_t)(m0 + row) * 1024 + k0 + scol;
            g2lds16(ga, &Alds[chunk * 512]);
            const int brow = n0 + row;
            const u16* gb = (brow < nsplit ? B0 + (size_t)brow * 1024
                                           : B1 + (size_t)(brow - nsplit) * 1024)
                            + k0 + scol;
            g2lds16(gb, &Blds[chunk * 512]);
        }
        __syncthreads();

#pragma unroll
        for (int kk = 0; kk < 64; kk += 32) {
            bf16x8 af[4], bfr[4];
#pragma unroll
            for (int mb = 0; mb < 4; ++mb)
                af[mb] = *(const bf16x8*)&Alds[(mrow0 + mb * 16 + l15) * 64 + kk + quad * 8];
#pragma unroll
            for (int nb = 0; nb < 4; ++nb)
                bfr[nb] = *(const bf16x8*)&Blds[(ncol0 + nb * 16 + l15) * 64 + kk + quad * 8];
#pragma unroll
            for (int mb = 0; mb < 4; ++mb)
#pragma unroll
                for (int nb = 0; nb < 4; ++nb)
                    acc[mb][nb] = __builtin_amdgcn_mfma_f32_16x16x32_bf16(
                        af[mb], bfr[nb], acc[mb][nb], 0, 0, 0);
        }
    }

    // epilogue: C/D layout col=lane&15, row=quad*4+reg
#pragma unroll
    for (int mb = 0; mb < 4; ++mb)
#pragma unroll
        for (int nb = 0; nb < 4; ++nb)
#pragma unroll
            for (int r = 0; r < 4; ++r) {
                const int row = m0 + mrow0 + mb * 16 + quad * 4 + r;
                const int col = n0 + ncol0 + nb * 16 + l15;
                const u16 v = f2bf(acc[mb][nb][r]);
                if (MODE == 1) {
                    const int h = col & 63;
                    u16* dst = (col < 64) ? D0 : D1;
                    const size_t idx = (size_t)((row >> 4) * 2 + (h >> 5)) * 512
                                     + ((row & 15) + ((h >> 3) & 3) * 16) * 8
                                     + (h & 7);
                    dst[idx] = v;
                } else {
                    const size_t idx = (size_t)((row >> 4) * 512 + (col >> 5)) * 512
                                     + ((row & 15) + ((col >> 3) & 3) * 16) * 8
                                     + (col & 7);
                    D0[idx] = v;
                }
            }
}

// Combined GEMM dispatch: blocks [0,128) -> QK projection, [128,1152) -> Vt.
__global__ __launch_bounds__(256, 2) void gemm_all(
    const u16* __restrict__ xb,
    const u16* __restrict__ Wqb, const u16* __restrict__ Wkb,
    const u16* __restrict__ Wvb,
    u16* __restrict__ Qf, u16* __restrict__ Kf, u16* __restrict__ Vf)
{
    __shared__ u16 Alds[128 * 64];
    __shared__ u16 Blds[128 * 64];
    const int d = blockIdx.x;
    if (d < 128) {
        gemm_body<1>(d * 128, 0, xb, Wqb, Wkb, 64, Qf, Kf, Alds, Blds);
    } else {
        const int dd = d - 128;
        gemm_body<2>((dd >> 7) * 128, (dd & 127) * 128, Wvb, xb, xb, 1 << 30,
                     Vf, nullptr, Alds, Blds);
    }
}

// ----------------------------------------------------------------------------
// Flash attention, no-max softmax, LDS-staged V, LDS P handoff.
// 1024 blocks x 256 thr. Block = 128 q-rows x 128 e-cols:
//   b = d&3, e0 = (d>>2)&7 (e-base e0*128), g = d>>5, h=g&7, j=g>>3,
//   qt = {h, 31-h, 15-h, 16+h}[j]  (co-resident sum const -> balanced CUs).
// Wave (wr=w>>1, wc=w&1): S phase = rows [wr*64,+64) x s-cols [wc*16,+16);
// PV phase = rows [wr*64,+64) x e-cols [wc*64,+64). Same wr => same activity
// limit for producers and consumers (no stale P reads).
// ----------------------------------------------------------------------------
__global__ __launch_bounds__(256, 4) void attn_fa(
    const u16* __restrict__ Qf,
    const u16* __restrict__ Kf,
    const u16* __restrict__ Vf,
    float* __restrict__ Out)
{
    __shared__ u16 Vlds[2][8 * 512];    // 2 x 8KB  (128e x 32s)
    __shared__ u16 Plds[2][128 * 40];   // 2 x 10KB (128q x 32s, row-pad 40)

    const int tid  = threadIdx.x;
    const int lane = tid & 63, w = tid >> 6;
    const int quad = lane >> 4, l15 = lane & 15;

    const int d  = blockIdx.x;
    const int b  = d & 3;
    const int e0 = (d >> 2) & 7;
    const int g  = d >> 5;
    const int h  = g & 7, j = g >> 3;
    const int qt = (j == 0) ? h : (j == 1) ? 31 - h : (j == 2) ? 15 - h : 16 + h;
    const int bt0 = b * 4096;

    const int wr = w >> 1, wc = w & 1;
    const int qm0 = qt * 128 + wr * 64;       // wave's 64 q-rows (absolute)
    const int slim = qm0 + 63;                // active iff s0 <= slim

    const short o = (short)0x3F80;            // bf16 1.0
    const bf16x8 ones = {o, o, o, o, o, o, o, o};

    f32x4 acc[4][4] = {};                     // O accumulator [mb][nb]
    f32x4 accl[4] = {};                       // row sums

    const int ntiles = 4 * qt + 4;

    auto stageV = [&](int buf, int it) {
        const int stile = (bt0 + it * 32) >> 5;
#pragma unroll
        for (int t2 = 0; t2 < 2; ++t2) {
            const int t = w * 2 + t2;
            g2lds16(&Vf[(size_t)((e0 * 8 + t) * 512 + stile) * 512 + lane * 8],
                    &Vlds[buf][t * 512]);
        }
    };

    auto loadK = [&](int jt, bf16x8* kf) {    // this wave's 16 s-cols
#pragma unroll
        for (int kk = 0; kk < 2; ++kk) {
            const int kt = ((bt0 + jt * 32 + wc * 16) >> 4) * 2 + kk;
            kf[kk] = *(const bf16x8*)&Kf[(size_t)kt * 512 + lane * 8];
        }
    };

    auto computeP = [&](int jt, const bf16x8* kf) {
        const int s0 = jt * 32;
        f32x4 sf[4] = {};
#pragma unroll
        for (int mb = 0; mb < 4; ++mb) {
            const int btile = (bt0 + qm0 + mb * 16) >> 4;
#pragma unroll
            for (int kk = 0; kk < 2; ++kk) {
                const bf16x8 q = *(const bf16x8*)&Qf[(size_t)(btile * 2 + kk) * 512 + lane * 8];
                sf[mb] = __builtin_amdgcn_mfma_f32_16x16x32_bf16(
                    q, kf[kk], sf[mb], 0, 0, 0);
            }
        }
        if (s0 + wc * 16 + 15 > qm0) {        // diagonal-crossing: mask
            const int colabs = s0 + wc * 16 + l15;
#pragma unroll
            for (int mb = 0; mb < 4; ++mb)
#pragma unroll
                for (int r = 0; r < 4; ++r) {
                    const int rowabs = qm0 + mb * 16 + quad * 4 + r;
                    sf[mb][r] = (colabs <= rowabs) ? sf[mb][r] : -__builtin_inff();
                }
        }
        u16* Pl = &Plds[jt & 1][(wr * 64 + quad * 4) * 40 + wc * 16 + l15];
#pragma unroll
        for (int mb = 0; mb < 4; ++mb)
#pragma unroll
            for (int r = 0; r < 4; ++r)
                Pl[(mb * 16 + r) * 40] = f2bf(exp2f(sf[mb][r]));
    };

    // ---- prologue: tile 0 ----
    stageV(0, 0);
    {
        bf16x8 kf0[2];
        loadK(0, kf0);
        computeP(0, kf0);
    }

    for (int it = 0; it < ntiles; ++it) {
        __syncthreads();                      // publishes P(it), V(it)
        const int buf = it & 1;
        const bool haveNext = (it + 1 < ntiles);
        const bool nextAct = haveNext && ((it + 1) * 32 <= slim);
        const bool curAct  = (it * 32 <= slim);

        if (haveNext) stageV(buf ^ 1, it + 1);
        bf16x8 kf[2];
        if (nextAct) loadK(it + 1, kf);       // latency hidden by PV MFMAs

        if (curAct) {
            bf16x8 pf[4];
#pragma unroll
            for (int mb = 0; mb < 4; ++mb)
                pf[mb] = *(const bf16x8*)&Plds[buf][(wr * 64 + mb * 16 + l15) * 40 + quad * 8];
#pragma unroll
            for (int mb = 0; mb < 4; ++mb)
                accl[mb] = __builtin_amdgcn_mfma_f32_16x16x32_bf16(
                    pf[mb], ones, accl[mb], 0, 0, 0);
#pragma unroll
            for (int nb = 0; nb < 4; ++nb) {
                const bf16x8 vf = *(const bf16x8*)&Vlds[buf][(wc * 4 + nb) * 512 + lane * 8];
#pragma unroll
                for (int mb = 0; mb < 4; ++mb)
                    acc[mb][nb] = __builtin_amdgcn_mfma_f32_16x16x32_bf16(
                        pf[mb], vf, acc[mb][nb], 0, 0, 0);
            }
        }

        if (nextAct) computeP(it + 1, kf);
    }

    // ---- epilogue: normalize by row sums ----
#pragma unroll
    for (int mb = 0; mb < 4; ++mb) {
        float rl[4];
#pragma unroll
        for (int r = 0; r < 4; ++r) rl[r] = 1.0f / accl[mb][r];
#pragma unroll
        for (int nb = 0; nb < 4; ++nb)
#pragma unroll
            for (int r = 0; r < 4; ++r) {
                const int row = qm0 + mb * 16 + quad * 4 + r;
                const int col = e0 * 128 + wc * 64 + nb * 16 + l15;
                Out[(size_t)(bt0 + row) * 1024 + col] = acc[mb][nb][r] * rl[r];
            }
    }
}

// ----------------------------------------------------------------------------
extern "C" void kernel_launch(void* const* d_in, const int* in_sizes, int n_in,
                              void* d_out, int out_size, void* d_ws, size_t ws_size,
                              hipStream_t stream) {
    const float* x  = (const float*)d_in[0];   // [4,4096,1024]
    const float* Wk = (const float*)d_in[1];   // [64,1024]
    const float* Wq = (const float*)d_in[2];   // [64,1024]
    const float* Wv = (const float*)d_in[3];   // [1024,1024]

    const int nx  = in_sizes[0];
    const int nwk = in_sizes[1];
    const int nwq = in_sizes[2];
    const int nwv = in_sizes[3];

    u16* xb  = (u16*)d_ws;
    u16* Wkb = xb  + (size_t)nx;
    u16* Wqb = Wkb + (size_t)nwk;
    u16* Wvb = Wqb + (size_t)nwq;
    u16* Qf  = Wvb + (size_t)nwv;                    // 1024 btiles * 2 * 512
    u16* Kf  = Qf  + (size_t)1024 * 2 * 512;
    u16* Vf  = Kf  + (size_t)1024 * 2 * 512;         // 64 etiles * 512 * 512
    float* out = (float*)d_out;

    const float qscale = 0.125f * 1.44269504088896f; // fold 1/sqrt(H)*log2(e)

    cvt_x<<<nx / 1024, 256, 0, stream>>>(x, xb, nx);
    cvt_w<<<(nwk + nwq + nwv) / 1024, 256, 0, stream>>>(Wk, Wq, Wv,
                                                        Wkb, Wqb, Wvb, qscale);

    gemm_all<<<1152, 256, 0, stream>>>(xb, Wqb, Wkb, Wvb, Qf, Kf, Vf);

    attn_fa<<<1024, 256, 0, stream>>>(Qf, Kf, Vf, out);
}